// Round 9
// baseline (270.509 us; speedup 1.0000x reference)
//
#include <hip/hip_runtime.h>

typedef __bf16 bf16;
typedef __attribute__((ext_vector_type(8))) __bf16 bf16x8;
typedef __attribute__((ext_vector_type(4))) float f32x4;
typedef __attribute__((ext_vector_type(4))) unsigned short u16x4;

#define D_MODEL 1024
#define SEQ     2048
#define NB      4
#define NH      16
#define DK      64
#define MROWS   (NB * SEQ)   // 8192

#define MFMA_BF16 __builtin_amdgcn_mfma_f32_16x16x32_bf16
#define EXP2F(x) __builtin_amdgcn_exp2f(x)
#define QSCALE 0.18033688011112042f   // 0.125 * log2(e)

__device__ __forceinline__ bf16 f2b(float f) {
    union { float f; unsigned u; } c; c.f = f;
    unsigned r = (c.u + 0x7fffu + ((c.u >> 16) & 1u)) >> 16;
    union { unsigned short s; bf16 b; } o; o.s = (unsigned short)r;
    return o.b;
}
__device__ __forceinline__ unsigned short f2u(float f) {
    union { float f; unsigned u; } c; c.f = f;
    return (unsigned short)((c.u + 0x7fffu + ((c.u >> 16) & 1u)) >> 16);
}
__device__ __forceinline__ unsigned fbits(float f) {
    union { float f; unsigned u; } c; c.f = f; return c.u;
}
__device__ __forceinline__ unsigned pack2(float lo, float hi) {
    return __builtin_amdgcn_perm(fbits(hi), fbits(lo), 0x07060302u);
}

// ---------------------------------------------------------------- prep (fused)
__global__ void prep_kernel(const float* __restrict__ X,
                            const float* __restrict__ Wq, const float* __restrict__ Wk,
                            const float* __restrict__ Wv, const float* __restrict__ Wo,
                            bf16* __restrict__ Xb, bf16* __restrict__ WqkvT,
                            bf16* __restrict__ WoT) {
    __shared__ float tile[32][33];
    const int bid = blockIdx.x;
    if (bid < 8192) {
        int i = bid * 256 + threadIdx.x;
        float4 v = ((const float4*)X)[i];
        u16x4 o; o[0] = f2u(v.x); o[1] = f2u(v.y); o[2] = f2u(v.z); o[3] = f2u(v.w);
        ((u16x4*)Xb)[i] = o;
    } else {
        int r = bid - 8192;
        int w = r >> 10, tl = r & 1023;
        const float* src = (w == 0) ? Wq : (w == 1) ? Wk : (w == 2) ? Wv : Wo;
        bf16* dst = (w == 3) ? WoT : WqkvT + (size_t)w * 1024 * 1024;
        const int n0 = (tl & 31) * 32, k0 = (tl >> 5) * 32;
        const int tx = threadIdx.x & 31, ty = threadIdx.x >> 5;
#pragma unroll
        for (int i = 0; i < 4; i++)
            tile[ty + i * 8][tx] = src[(size_t)(k0 + ty + i * 8) * 1024 + n0 + tx];
        __syncthreads();
#pragma unroll
        for (int i = 0; i < 4; i++)
            dst[(size_t)(n0 + ty + i * 8) * 1024 + k0 + tx] = f2b(tile[tx][ty + i * 8]);
    }
}

// ---------------------------------------------------------------- fused QKV GEMM
// (unchanged from R8 — <=78us, near K=1024 plateau)
__global__ __launch_bounds__(256) void gemm_qkv(const bf16* __restrict__ A,
                                                const bf16* __restrict__ Bt,
                                                bf16* __restrict__ outQ,
                                                bf16* __restrict__ outV) {
    __shared__ __align__(16) bf16 lA[128 * 64];
    __shared__ __align__(16) bf16 lB[128 * 64];

    const int t = threadIdx.x;
    const int wid = t >> 6, lane = t & 63;
    const int ln = lane & 15, qd = lane >> 4;
    const int wm = wid >> 1, wn = wid & 1;

    const int bid = blockIdx.x;
    const int idx = bid >> 3;
    const int colb = (bid & 7) * 3 + (idx % 3);
    const int rowb = idx / 3;
    const int row0 = rowb * 128, col0 = colb * 128;
    const bool isQK = (col0 < 2048);

    const int srow = t >> 3;
    const int schunk = (t & 7) ^ (srow & 7);
    const bf16* ga = A  + (size_t)(row0 + srow) * 1024 + schunk * 8;
    const bf16* gb = Bt + (size_t)(col0 + srow) * 1024 + schunk * 8;
    const int swk = ln & 7;

    f32x4 acc[4][4];
#pragma unroll
    for (int i = 0; i < 4; i++)
#pragma unroll
        for (int j = 0; j < 4; j++) acc[i][j] = (f32x4){0.f, 0.f, 0.f, 0.f};

    for (int kb = 0; kb < 1024; kb += 64) {
#pragma unroll
        for (int c = 0; c < 4; c++) {
            __builtin_amdgcn_global_load_lds(
                (const __attribute__((address_space(1))) void*)(ga + kb + (size_t)c * 32 * 1024),
                (__attribute__((address_space(3))) void*)(&lA[t * 8 + c * 2048]), 16, 0, 0);
            __builtin_amdgcn_global_load_lds(
                (const __attribute__((address_space(1))) void*)(gb + kb + (size_t)c * 32 * 1024),
                (__attribute__((address_space(3))) void*)(&lB[t * 8 + c * 2048]), 16, 0, 0);
        }
        __syncthreads();

#pragma unroll
        for (int ks = 0; ks < 2; ks++) {
            bf16x8 af[4], bfr[4];
#pragma unroll
            for (int i = 0; i < 4; i++)
                af[i] = *(const bf16x8*)&lA[(wm * 64 + i * 16 + ln) * 64
                                            + ((ks * 4 + qd) ^ swk) * 8];
#pragma unroll
            for (int j = 0; j < 4; j++)
                bfr[j] = *(const bf16x8*)&lB[(wn * 64 + j * 16 + ln) * 64
                                             + ((ks * 4 + qd) ^ swk) * 8];
            if (isQK) {
#pragma unroll
                for (int i = 0; i < 4; i++)
#pragma unroll
                    for (int j = 0; j < 4; j++)
                        acc[i][j] = MFMA_BF16(bfr[j], af[i], acc[i][j], 0, 0, 0);
            } else {
#pragma unroll
                for (int i = 0; i < 4; i++)
#pragma unroll
                    for (int j = 0; j < 4; j++)
                        acc[i][j] = MFMA_BF16(af[i], bfr[j], acc[i][j], 0, 0, 0);
            }
        }
        __syncthreads();
    }

    if (isQK) {
#pragma unroll
        for (int i = 0; i < 4; i++)
#pragma unroll
            for (int j = 0; j < 4; j++) {
                int m  = row0 + wm * 64 + i * 16 + ln;
                int n0 = col0 + wn * 64 + j * 16 + qd * 4;
                float scale = (n0 < 1024) ? QSCALE : 1.0f;
                int b = m >> 11, s = m & 2047;
                int h = (n0 & 1023) >> 6, d0 = n0 & 63;
                size_t addr = (((size_t)(b * NH + h) * SEQ + s) * DK + d0)
                              + (size_t)(n0 >> 10) * 8388608;
                u16x4 w;
#pragma unroll
                for (int r = 0; r < 4; r++) w[r] = f2u(acc[i][j][r] * scale);
                *(u16x4*)&outQ[addr] = w;
            }
    } else {
#pragma unroll
        for (int i = 0; i < 4; i++)
#pragma unroll
            for (int j = 0; j < 4; j++) {
                int m0 = row0 + wm * 64 + i * 16 + qd * 4;
                int n  = col0 + wn * 64 + j * 16 + ln - 2048;
                int b = m0 >> 11, s0 = m0 & 2047;
                int h = n >> 6, d = n & 63;
                size_t addr = ((size_t)(b * NH + h) * DK + d) * SEQ + s0;
                u16x4 w;
#pragma unroll
                for (int r = 0; r < 4; r++) w[r] = f2u(acc[i][j][r]);
                *(u16x4*)&outV[addr] = w;
            }
    }
}

// ---------------------------------------------------------------- output GEMM
// out[8192,1024] fp32 = Attn * Wo^T. 128x64 tile, 1024 blocks (~5 blocks/CU
// co-residency to hide barrier drains). Wave w: rows [w*32,w*32+32) x 64 cols
// (2x4 frags, 32 acc VGPR). LDS 24 KB. XCD-pinned 2-col strips.
__global__ __launch_bounds__(256) void gemm_o(const bf16* __restrict__ A,
                                              const bf16* __restrict__ Bt,
                                              float* __restrict__ out) {
    __shared__ __align__(16) bf16 lA[128 * 64];   // 16 KB
    __shared__ __align__(16) bf16 lB[64 * 64];    //  8 KB

    const int t = threadIdx.x;
    const int wid = t >> 6, lane = t & 63;
    const int ln = lane & 15, qd = lane >> 4;

    const int bid = blockIdx.x;
    const int idx = bid >> 3;
    const int colb = (bid & 7) * 2 + (idx & 1);
    const int rowb = idx >> 1;
    const int row0 = rowb * 128, col0 = colb * 64;

    const int srow = t >> 3;
    const int schunk = (t & 7) ^ (srow & 7);
    const bf16* ga = A  + (size_t)(row0 + srow) * 1024 + schunk * 8;
    const bf16* gb = Bt + (size_t)(col0 + srow) * 1024 + schunk * 8;
    const int swk = ln & 7;

    f32x4 acc[2][4];
#pragma unroll
    for (int i = 0; i < 2; i++)
#pragma unroll
        for (int j = 0; j < 4; j++) acc[i][j] = (f32x4){0.f, 0.f, 0.f, 0.f};

    for (int kb = 0; kb < 1024; kb += 64) {
#pragma unroll
        for (int c = 0; c < 4; c++)
            __builtin_amdgcn_global_load_lds(
                (const __attribute__((address_space(1))) void*)(ga + kb + (size_t)c * 32 * 1024),
                (__attribute__((address_space(3))) void*)(&lA[t * 8 + c * 2048]), 16, 0, 0);
#pragma unroll
        for (int c = 0; c < 2; c++)
            __builtin_amdgcn_global_load_lds(
                (const __attribute__((address_space(1))) void*)(gb + kb + (size_t)c * 32 * 1024),
                (__attribute__((address_space(3))) void*)(&lB[t * 8 + c * 2048]), 16, 0, 0);
        __syncthreads();

#pragma unroll
        for (int ks = 0; ks < 2; ks++) {
            bf16x8 af[2], bfr[4];
#pragma unroll
            for (int i = 0; i < 2; i++)
                af[i] = *(const bf16x8*)&lA[(wid * 32 + i * 16 + ln) * 64
                                            + ((ks * 4 + qd) ^ swk) * 8];
#pragma unroll
            for (int j = 0; j < 4; j++)
                bfr[j] = *(const bf16x8*)&lB[(j * 16 + ln) * 64
                                             + ((ks * 4 + qd) ^ swk) * 8];
#pragma unroll
            for (int i = 0; i < 2; i++)
#pragma unroll
                for (int j = 0; j < 4; j++)
                    acc[i][j] = MFMA_BF16(bfr[j], af[i], acc[i][j], 0, 0, 0);
        }
        __syncthreads();
    }

#pragma unroll
    for (int i = 0; i < 2; i++)
#pragma unroll
        for (int j = 0; j < 4; j++) {
            int m  = row0 + wid * 32 + i * 16 + ln;
            int n0 = col0 + j * 16 + qd * 4;
            *(f32x4*)&out[(size_t)m * 1024 + n0] = acc[i][j];
        }
}

// ---------------------------------------------------------------- attention
// R6 structure (33 uniform 64-key steps, fixed-m softmax, v_perm P pack) with
// incrementally-advanced staging pointers (single reset at group boundary)
// replacing per-step piecewise address reconstruction.
__global__ __launch_bounds__(256) void attn_kernel(const bf16* __restrict__ Q,
                                                   const bf16* __restrict__ K,
                                                   const bf16* __restrict__ Vt,
                                                   bf16* __restrict__ attn_out) {
    __shared__ __align__(16) bf16 kbuf[2][64 * 64];
    __shared__ __align__(16) bf16 vbuf[2][64 * 64];
    __shared__ __align__(16) bf16 plds[4][16 * 64];

    const int t = threadIdx.x;
    const int wid = t >> 6, lane = t & 63;
    const int ln = lane & 15, qd = lane >> 4;

    const int bid = blockIdx.x;
    const int bh   = ((bid >> 7) << 3) | (bid & 7);   // XCD swizzle
    const int pair = (bid >> 3) & 15;
    const int gA = pair, gB = 31 - pair;
    const int ntA = gA + 1, ntT = 33;

    const bf16* Qh = Q  + (size_t)bh * SEQ * DK;
    const bf16* Kh = K  + (size_t)bh * SEQ * DK;
    const bf16* Vh = Vt + (size_t)bh * DK * SEQ;
    bf16* pw = &plds[wid][0];

    const int srow = t >> 3;
    const int schunk = (t & 7) ^ (srow & 7);
    const bf16* kgp = Kh + (size_t)srow * DK + schunk * 8;
    const bf16* vgp = Vh + (size_t)srow * SEQ + schunk * 8;
    const int swk = ln & 7;

    f32x4 o[4];
    float l;
    int qw0;
    bf16x8 qf0, qf1;

    auto stage = [&](const bf16* sk, const bf16* sv, int buf) {
#pragma unroll
        for (int c = 0; c < 2; c++) {
            __builtin_amdgcn_global_load_lds(
                (const __attribute__((address_space(1))) void*)(sk + (size_t)c * 32 * DK),
                (__attribute__((address_space(3))) void*)(&kbuf[buf][t * 8 + c * 2048]), 16, 0, 0);
            __builtin_amdgcn_global_load_lds(
                (const __attribute__((address_space(1))) void*)(sv + (size_t)c * 32 * SEQ),
                (__attribute__((address_space(3))) void*)(&vbuf[buf][t * 8 + c * 2048]), 16, 0, 0);
        }
    };
    auto initGroup = [&](int g) {
        qw0 = g * 64 + wid * 16;
        qf0 = *(const bf16x8*)(Qh + (size_t)(qw0 + ln) * DK + qd * 8);
        qf1 = *(const bf16x8*)(Qh + (size_t)(qw0 + ln) * DK + 32 + qd * 8);
#pragma unroll
        for (int c = 0; c < 4; c++) o[c] = (f32x4){0.f, 0.f, 0.f, 0.f};
        l = 0.f;
    };
    const int b = bh >> 4, h = bh & 15;
    auto finalize = [&]() {
        float ll = l;
        ll += __shfl_xor(ll, 16);
        ll += __shfl_xor(ll, 32);
        float inv = 1.0f / ll;
        size_t orow = ((size_t)(b * SEQ + qw0 + ln)) * D_MODEL + h * DK;
#pragma unroll
        for (int c = 0; c < 4; c++) {
            u16x4 w;
#pragma unroll
            for (int r = 0; r < 4; r++) w[r] = f2u(o[c][r] * inv);
            *(u16x4*)&attn_out[orow + c * 16 + qd * 4] = w;
        }
    };

    const bf16* sk = kgp;
    const bf16* sv = vgp;
    stage(sk, sv, 0);
    sk += (size_t)64 * DK; sv += 64;
    initGroup(gA);
    int cur = 0;
    int kbc = 0;                 // kb of the step being computed

    for (int i = 0; i < ntT; i++) {
        __syncthreads();
        int nx = i + 1;
        if (nx < ntT) {
            if (nx == ntA) { sk = kgp; sv = vgp; }
            stage(sk, sv, cur ^ 1);
            sk += (size_t)64 * DK; sv += 64;
        }
        const int kb = kbc;
        const int nkk = min(4, max(0, ((qw0 + 15 - kb) >> 4) + 1));

        if (nkk > 0) {
            f32x4 st[4];
#pragma unroll
            for (int kk = 0; kk < 4; kk++)
                if (kk < nkk) {
                    const bf16* base = &kbuf[cur][(kk * 16 + ln) * 64];
                    bf16x8 kf0 = *(const bf16x8*)(base + ((qd    ) ^ swk) * 8);
                    bf16x8 kf1 = *(const bf16x8*)(base + ((qd + 4) ^ swk) * 8);
                    f32x4 z = (f32x4){0.f, 0.f, 0.f, 0.f};
                    st[kk] = MFMA_BF16(kf0, qf0, z, 0, 0, 0);
                    st[kk] = MFMA_BF16(kf1, qf1, st[kk], 0, 0, 0);
                }

            float ps = 0.f;
#pragma unroll
            for (int kk = 0; kk < 4; kk++) {
                unsigned pk0 = 0, pk1 = 0;
                if (kk < nkk) {
                    f32x4 s = st[kk];
                    if (kb + kk * 16 == qw0) {
#pragma unroll
                        for (int r = 0; r < 4; r++)
                            if (qd * 4 + r > ln) s[r] = -INFINITY;
                    }
                    float p0 = EXP2F(s[0]);
                    float p1 = EXP2F(s[1]);
                    float p2 = EXP2F(s[2]);
                    float p3 = EXP2F(s[3]);
                    ps += (p0 + p1) + (p2 + p3);
                    pk0 = pack2(p0, p1);
                    pk1 = pack2(p2, p3);
                }
                int cw = 2 * kk + (qd >> 1);
                *(uint2*)&pw[ln * 64 + (cw ^ swk) * 8 + (qd & 1) * 4] =
                    make_uint2(pk0, pk1);
            }
            l += ps;

            asm volatile("s_waitcnt lgkmcnt(0)" ::: "memory");

#pragma unroll
            for (int half = 0; half < 2; half++)
                if (half == 0 || nkk > 2) {
                    bf16x8 pa = *(const bf16x8*)&pw[ln * 64 + ((half * 4 + qd) ^ swk) * 8];
#pragma unroll
                    for (int c = 0; c < 4; c++) {
                        bf16x8 vf = *(const bf16x8*)&vbuf[cur][(c * 16 + ln) * 64
                                        + ((half * 4 + qd) ^ swk) * 8];
                        o[c] = MFMA_BF16(vf, pa, o[c], 0, 0, 0);
                    }
                }
        }

        if (i == ntA - 1) { finalize(); initGroup(gB); kbc = 0; }
        else kbc += 64;
        cur ^= 1;
    }
    finalize();
}

// ---------------------------------------------------------------- launch
extern "C" void kernel_launch(void* const* d_in, const int* in_sizes, int n_in,
                              void* d_out, int out_size, void* d_ws, size_t ws_size,
                              hipStream_t stream) {
    const float* X  = (const float*)d_in[0];
    const float* Wq = (const float*)d_in[1];
    const float* Wk = (const float*)d_in[2];
    const float* Wv = (const float*)d_in[3];
    const float* Wo = (const float*)d_in[4];
    float* out = (float*)d_out;
    char* ws = (char*)d_ws;

    bf16* Xb    = (bf16*)(ws);                    // 16 MB (reused as Attn)
    bf16* WqkvT = (bf16*)(ws + (16u << 20));      //  6 MB [3072][1024]
    bf16* WoT   = (bf16*)(ws + (22u << 20));      //  2 MB
    bf16* Qb    = (bf16*)(ws + (24u << 20));      // 16 MB [bh][s][dk] (pre-scaled)
    bf16* Vt    = (bf16*)(ws + (56u << 20));      // 16 MB [bh][dk][s]
    bf16* Attn  = Xb;
    bf16* Kb    = Qb + (size_t)8388608;           // fused-QK second half

    prep_kernel<<<dim3(12288), dim3(256), 0, stream>>>(X, Wq, Wk, Wv, Wo,
                                                       Xb, WqkvT, WoT);

    gemm_qkv<<<dim3(1536), dim3(256), 0, stream>>>(Xb, WqkvT, Qb, Vt);

    attn_kernel<<<dim3(1024), dim3(256), 0, stream>>>(Qb, Kb, Vt, Attn);

    gemm_o<<<dim3(1024), dim3(256), 0, stream>>>(Attn, WoT, out);
}

// Round 10
// 263.271 us; speedup vs baseline: 1.0275x; 1.0275x over previous
//
#include <hip/hip_runtime.h>

typedef __bf16 bf16;
typedef __attribute__((ext_vector_type(8))) __bf16 bf16x8;
typedef __attribute__((ext_vector_type(4))) float f32x4;
typedef __attribute__((ext_vector_type(4))) unsigned short u16x4;

#define D_MODEL 1024
#define SEQ     2048
#define NB      4
#define NH      16
#define DK      64
#define MROWS   (NB * SEQ)   // 8192

#define MFMA_BF16 __builtin_amdgcn_mfma_f32_16x16x32_bf16
#define EXP2F(x) __builtin_amdgcn_exp2f(x)
#define QSCALE 0.18033688011112042f   // 0.125 * log2(e)

__device__ __forceinline__ bf16 f2b(float f) {
    union { float f; unsigned u; } c; c.f = f;
    unsigned r = (c.u + 0x7fffu + ((c.u >> 16) & 1u)) >> 16;
    union { unsigned short s; bf16 b; } o; o.s = (unsigned short)r;
    return o.b;
}
__device__ __forceinline__ unsigned short f2u(float f) {
    union { float f; unsigned u; } c; c.f = f;
    return (unsigned short)((c.u + 0x7fffu + ((c.u >> 16) & 1u)) >> 16);
}
__device__ __forceinline__ unsigned fbits(float f) {
    union { float f; unsigned u; } c; c.f = f; return c.u;
}
// pack two fp32 -> two bf16 (truncation) in one v_perm_b32
__device__ __forceinline__ unsigned pack2(float lo, float hi) {
    return __builtin_amdgcn_perm(fbits(hi), fbits(lo), 0x07060302u);
}

// ---------------------------------------------------------------- prep (fused)
// blocks [0,8192): X fp32->bf16. blocks [8192,12288): weight transposes into
// WqkvT (3072x1024, rows 0-1023=Wq, 1024-2047=Wk, 2048-3071=Wv) and WoT.
__global__ void prep_kernel(const float* __restrict__ X,
                            const float* __restrict__ Wq, const float* __restrict__ Wk,
                            const float* __restrict__ Wv, const float* __restrict__ Wo,
                            bf16* __restrict__ Xb, bf16* __restrict__ WqkvT,
                            bf16* __restrict__ WoT) {
    __shared__ float tile[32][33];
    const int bid = blockIdx.x;
    if (bid < 8192) {
        int i = bid * 256 + threadIdx.x;
        float4 v = ((const float4*)X)[i];
        u16x4 o; o[0] = f2u(v.x); o[1] = f2u(v.y); o[2] = f2u(v.z); o[3] = f2u(v.w);
        ((u16x4*)Xb)[i] = o;
    } else {
        int r = bid - 8192;
        int w = r >> 10, tl = r & 1023;
        const float* src = (w == 0) ? Wq : (w == 1) ? Wk : (w == 2) ? Wv : Wo;
        bf16* dst = (w == 3) ? WoT : WqkvT + (size_t)w * 1024 * 1024;
        const int n0 = (tl & 31) * 32, k0 = (tl >> 5) * 32;
        const int tx = threadIdx.x & 31, ty = threadIdx.x >> 5;
#pragma unroll
        for (int i = 0; i < 4; i++)
            tile[ty + i * 8][tx] = src[(size_t)(k0 + ty + i * 8) * 1024 + n0 + tx];
        __syncthreads();
#pragma unroll
        for (int i = 0; i < 4; i++)
            dst[(size_t)(n0 + ty + i * 8) * 1024 + k0 + tx] = f2b(tile[tx][ty + i * 8]);
    }
}

// ---------------------------------------------------------------- fused QKV GEMM
// C[8192,3072] = Xb * [Wq;Wk;Wv]^T. 128x128 tile, BK=64, source-side XOR
// swizzle. 1536 blocks, XCD-pinned columns (xcd = bid&7 owns 3 col strips =
// 768 KB of B resident in its L2; X row strips reused 3x in-XCD).
// Cols [0,2048): Q/K -> swapped MFMA orientation (reg<->d), bf16 [proj][bh][s][dk].
// Cols [2048,3072): V -> normal orientation (reg<->s), bf16 [bh][dk][s].
__global__ __launch_bounds__(256) void gemm_qkv(const bf16* __restrict__ A,
                                                const bf16* __restrict__ Bt,
                                                bf16* __restrict__ outQ,
                                                bf16* __restrict__ outV) {
    __shared__ __align__(16) bf16 lA[128 * 64];
    __shared__ __align__(16) bf16 lB[128 * 64];

    const int t = threadIdx.x;
    const int wid = t >> 6, lane = t & 63;
    const int ln = lane & 15, qd = lane >> 4;
    const int wm = wid >> 1, wn = wid & 1;

    const int bid = blockIdx.x;
    const int idx = bid >> 3;
    const int colb = (bid & 7) * 3 + (idx % 3);
    const int rowb = idx / 3;
    const int row0 = rowb * 128, col0 = colb * 128;
    const bool isQK = (col0 < 2048);

    const int srow = t >> 3;
    const int schunk = (t & 7) ^ (srow & 7);
    const bf16* ga = A  + (size_t)(row0 + srow) * 1024 + schunk * 8;
    const bf16* gb = Bt + (size_t)(col0 + srow) * 1024 + schunk * 8;
    const int swk = ln & 7;

    f32x4 acc[4][4];
#pragma unroll
    for (int i = 0; i < 4; i++)
#pragma unroll
        for (int j = 0; j < 4; j++) acc[i][j] = (f32x4){0.f, 0.f, 0.f, 0.f};

    for (int kb = 0; kb < 1024; kb += 64) {
#pragma unroll
        for (int c = 0; c < 4; c++) {
            __builtin_amdgcn_global_load_lds(
                (const __attribute__((address_space(1))) void*)(ga + kb + (size_t)c * 32 * 1024),
                (__attribute__((address_space(3))) void*)(&lA[t * 8 + c * 2048]), 16, 0, 0);
            __builtin_amdgcn_global_load_lds(
                (const __attribute__((address_space(1))) void*)(gb + kb + (size_t)c * 32 * 1024),
                (__attribute__((address_space(3))) void*)(&lB[t * 8 + c * 2048]), 16, 0, 0);
        }
        __syncthreads();

#pragma unroll
        for (int ks = 0; ks < 2; ks++) {
            bf16x8 af[4], bfr[4];
#pragma unroll
            for (int i = 0; i < 4; i++)
                af[i] = *(const bf16x8*)&lA[(wm * 64 + i * 16 + ln) * 64
                                            + ((ks * 4 + qd) ^ swk) * 8];
#pragma unroll
            for (int j = 0; j < 4; j++)
                bfr[j] = *(const bf16x8*)&lB[(wn * 64 + j * 16 + ln) * 64
                                             + ((ks * 4 + qd) ^ swk) * 8];
            if (isQK) {
#pragma unroll
                for (int i = 0; i < 4; i++)
#pragma unroll
                    for (int j = 0; j < 4; j++)
                        acc[i][j] = MFMA_BF16(bfr[j], af[i], acc[i][j], 0, 0, 0);
            } else {
#pragma unroll
                for (int i = 0; i < 4; i++)
#pragma unroll
                    for (int j = 0; j < 4; j++)
                        acc[i][j] = MFMA_BF16(af[i], bfr[j], acc[i][j], 0, 0, 0);
            }
        }
        __syncthreads();
    }

    if (isQK) {
#pragma unroll
        for (int i = 0; i < 4; i++)
#pragma unroll
            for (int j = 0; j < 4; j++) {
                int m  = row0 + wm * 64 + i * 16 + ln;
                int n0 = col0 + wn * 64 + j * 16 + qd * 4;
                float scale = (n0 < 1024) ? QSCALE : 1.0f;
                int b = m >> 11, s = m & 2047;
                int h = (n0 & 1023) >> 6, d0 = n0 & 63;
                size_t addr = (((size_t)(b * NH + h) * SEQ + s) * DK + d0)
                              + (size_t)(n0 >> 10) * 8388608;
                u16x4 w;
#pragma unroll
                for (int r = 0; r < 4; r++) w[r] = f2u(acc[i][j][r] * scale);
                *(u16x4*)&outQ[addr] = w;
            }
    } else {
#pragma unroll
        for (int i = 0; i < 4; i++)
#pragma unroll
            for (int j = 0; j < 4; j++) {
                int m0 = row0 + wm * 64 + i * 16 + qd * 4;
                int n  = col0 + wn * 64 + j * 16 + ln - 2048;
                int b = m0 >> 11, s0 = m0 & 2047;
                int h = n >> 6, d = n & 63;
                size_t addr = ((size_t)(b * NH + h) * DK + d) * SEQ + s0;
                u16x4 w;
#pragma unroll
                for (int r = 0; r < 4; r++) w[r] = f2u(acc[i][j][r]);
                *(u16x4*)&outV[addr] = w;
            }
    }
}

// ---------------------------------------------------------------- output GEMM
// out[8192,1024] fp32 = Attn * Wo^T. 128x128 tile, swapped orientation ->
// f32x4 stores. 512 blocks, XCD-pinned columns. (R8 config — the 128x64
// retile regressed: smaller tiles double staging rounds/barrier drains.)
__global__ __launch_bounds__(256) void gemm_o(const bf16* __restrict__ A,
                                              const bf16* __restrict__ Bt,
                                              float* __restrict__ out) {
    __shared__ __align__(16) bf16 lA[128 * 64];
    __shared__ __align__(16) bf16 lB[128 * 64];

    const int t = threadIdx.x;
    const int wid = t >> 6, lane = t & 63;
    const int ln = lane & 15, qd = lane >> 4;
    const int wm = wid >> 1, wn = wid & 1;

    const int bid = blockIdx.x;
    const int colb = bid & 7, rowb = bid >> 3;
    const int row0 = rowb * 128, col0 = colb * 128;

    const int srow = t >> 3;
    const int schunk = (t & 7) ^ (srow & 7);
    const bf16* ga = A  + (size_t)(row0 + srow) * 1024 + schunk * 8;
    const bf16* gb = Bt + (size_t)(col0 + srow) * 1024 + schunk * 8;
    const int swk = ln & 7;

    f32x4 acc[4][4];
#pragma unroll
    for (int i = 0; i < 4; i++)
#pragma unroll
        for (int j = 0; j < 4; j++) acc[i][j] = (f32x4){0.f, 0.f, 0.f, 0.f};

    for (int kb = 0; kb < 1024; kb += 64) {
#pragma unroll
        for (int c = 0; c < 4; c++) {
            __builtin_amdgcn_global_load_lds(
                (const __attribute__((address_space(1))) void*)(ga + kb + (size_t)c * 32 * 1024),
                (__attribute__((address_space(3))) void*)(&lA[t * 8 + c * 2048]), 16, 0, 0);
            __builtin_amdgcn_global_load_lds(
                (const __attribute__((address_space(1))) void*)(gb + kb + (size_t)c * 32 * 1024),
                (__attribute__((address_space(3))) void*)(&lB[t * 8 + c * 2048]), 16, 0, 0);
        }
        __syncthreads();

#pragma unroll
        for (int ks = 0; ks < 2; ks++) {
            bf16x8 af[4], bfr[4];
#pragma unroll
            for (int i = 0; i < 4; i++)
                af[i] = *(const bf16x8*)&lA[(wm * 64 + i * 16 + ln) * 64
                                            + ((ks * 4 + qd) ^ swk) * 8];
#pragma unroll
            for (int j = 0; j < 4; j++)
                bfr[j] = *(const bf16x8*)&lB[(wn * 64 + j * 16 + ln) * 64
                                             + ((ks * 4 + qd) ^ swk) * 8];
#pragma unroll
            for (int i = 0; i < 4; i++)
#pragma unroll
                for (int j = 0; j < 4; j++)
                    acc[i][j] = MFMA_BF16(bfr[j], af[i], acc[i][j], 0, 0, 0);
        }
        __syncthreads();
    }

#pragma unroll
    for (int i = 0; i < 4; i++)
#pragma unroll
        for (int j = 0; j < 4; j++) {
            int m  = row0 + wm * 64 + i * 16 + ln;
            int n0 = col0 + wn * 64 + j * 16 + qd * 4;
            *(f32x4*)&out[(size_t)m * 1024 + n0] = acc[i][j];
        }
}

// ---------------------------------------------------------------- attention
// (R6/R8 kernel — 78 µs known-good.) Block = 4 waves = one bh, one PAIR of
// 64-query groups (gA=p, gB=31-p): exactly 33 uniform 64-key steps. K/V
// double-buffered via global_load_lds (source-side XOR swizzle); fixed-m
// softmax; diagonal mask on single wave-uniform 16x16 block; P v_perm-packed
// into swizzled per-wave LDS; PV in two 32-key halves. 40 KB LDS -> 4 bl/CU.
__global__ __launch_bounds__(256) void attn_kernel(const bf16* __restrict__ Q,
                                                   const bf16* __restrict__ K,
                                                   const bf16* __restrict__ Vt,
                                                   bf16* __restrict__ attn_out) {
    __shared__ __align__(16) bf16 kbuf[2][64 * 64];
    __shared__ __align__(16) bf16 vbuf[2][64 * 64];
    __shared__ __align__(16) bf16 plds[4][16 * 64];

    const int t = threadIdx.x;
    const int wid = t >> 6, lane = t & 63;
    const int ln = lane & 15, qd = lane >> 4;

    const int bid = blockIdx.x;
    const int bh   = ((bid >> 7) << 3) | (bid & 7);   // XCD swizzle
    const int pair = (bid >> 3) & 15;
    const int gA = pair, gB = 31 - pair;
    const int ntA = gA + 1, ntT = 33;

    const bf16* Qh = Q  + (size_t)bh * SEQ * DK;
    const bf16* Kh = K  + (size_t)bh * SEQ * DK;
    const bf16* Vh = Vt + (size_t)bh * DK * SEQ;
    bf16* pw = &plds[wid][0];

    const int srow = t >> 3;
    const int schunk = (t & 7) ^ (srow & 7);
    const bf16* kgp = Kh + (size_t)srow * DK + schunk * 8;
    const bf16* vgp = Vh + (size_t)srow * SEQ + schunk * 8;
    const int swk = ln & 7;

    f32x4 o[4];
    float l;
    int qw0;
    bf16x8 qf0, qf1;

    auto stage = [&](int kb, int buf) {
#pragma unroll
        for (int c = 0; c < 2; c++) {
            __builtin_amdgcn_global_load_lds(
                (const __attribute__((address_space(1))) void*)(kgp + (size_t)(kb + c * 32) * DK),
                (__attribute__((address_space(3))) void*)(&kbuf[buf][t * 8 + c * 2048]), 16, 0, 0);
            __builtin_amdgcn_global_load_lds(
                (const __attribute__((address_space(1))) void*)(vgp + (size_t)c * 32 * SEQ + kb),
                (__attribute__((address_space(3))) void*)(&vbuf[buf][t * 8 + c * 2048]), 16, 0, 0);
        }
    };
    auto initGroup = [&](int g) {
        qw0 = g * 64 + wid * 16;
        qf0 = *(const bf16x8*)(Qh + (size_t)(qw0 + ln) * DK + qd * 8);
        qf1 = *(const bf16x8*)(Qh + (size_t)(qw0 + ln) * DK + 32 + qd * 8);
#pragma unroll
        for (int c = 0; c < 4; c++) o[c] = (f32x4){0.f, 0.f, 0.f, 0.f};
        l = 0.f;
    };
    const int b = bh >> 4, h = bh & 15;
    auto finalize = [&]() {
        float ll = l;
        ll += __shfl_xor(ll, 16);
        ll += __shfl_xor(ll, 32);
        float inv = 1.0f / ll;
        size_t orow = ((size_t)(b * SEQ + qw0 + ln)) * D_MODEL + h * DK;
#pragma unroll
        for (int c = 0; c < 4; c++) {
            u16x4 w;
#pragma unroll
            for (int r = 0; r < 4; r++) w[r] = f2u(o[c][r] * inv);
            *(u16x4*)&attn_out[orow + c * 16 + qd * 4] = w;
        }
    };

    stage(0, 0);
    initGroup(gA);
    int cur = 0;

    for (int i = 0; i < ntT; i++) {
        __syncthreads();
        int nx = i + 1;
        if (nx < ntT) {
            int kbn = ((nx < ntA) ? nx : nx - ntA) * 64;
            stage(kbn, cur ^ 1);
        }
        const int kb = ((i < ntA) ? i : i - ntA) * 64;
        const int nkk = min(4, max(0, ((qw0 + 15 - kb) >> 4) + 1));

        if (nkk > 0) {
            f32x4 st[4];
#pragma unroll
            for (int kk = 0; kk < 4; kk++)
                if (kk < nkk) {
                    const bf16* base = &kbuf[cur][(kk * 16 + ln) * 64];
                    bf16x8 kf0 = *(const bf16x8*)(base + ((qd    ) ^ swk) * 8);
                    bf16x8 kf1 = *(const bf16x8*)(base + ((qd + 4) ^ swk) * 8);
                    f32x4 z = (f32x4){0.f, 0.f, 0.f, 0.f};
                    st[kk] = MFMA_BF16(kf0, qf0, z, 0, 0, 0);
                    st[kk] = MFMA_BF16(kf1, qf1, st[kk], 0, 0, 0);
                }

            float ps = 0.f;
#pragma unroll
            for (int kk = 0; kk < 4; kk++) {
                unsigned pk0 = 0, pk1 = 0;
                if (kk < nkk) {
                    f32x4 s = st[kk];
                    if (kb + kk * 16 == qw0) {
#pragma unroll
                        for (int r = 0; r < 4; r++)
                            if (qd * 4 + r > ln) s[r] = -INFINITY;
                    }
                    float p0 = EXP2F(s[0]);
                    float p1 = EXP2F(s[1]);
                    float p2 = EXP2F(s[2]);
                    float p3 = EXP2F(s[3]);
                    ps += (p0 + p1) + (p2 + p3);
                    pk0 = pack2(p0, p1);
                    pk1 = pack2(p2, p3);
                }
                int cw = 2 * kk + (qd >> 1);
                *(uint2*)&pw[ln * 64 + (cw ^ swk) * 8 + (qd & 1) * 4] =
                    make_uint2(pk0, pk1);
            }
            l += ps;

            asm volatile("s_waitcnt lgkmcnt(0)" ::: "memory");

#pragma unroll
            for (int half = 0; half < 2; half++)
                if (half == 0 || nkk > 2) {
                    bf16x8 pa = *(const bf16x8*)&pw[ln * 64 + ((half * 4 + qd) ^ swk) * 8];
#pragma unroll
                    for (int c = 0; c < 4; c++) {
                        bf16x8 vf = *(const bf16x8*)&vbuf[cur][(c * 16 + ln) * 64
                                        + ((half * 4 + qd) ^ swk) * 8];
                        o[c] = MFMA_BF16(vf, pa, o[c], 0, 0, 0);
                    }
                }
        }

        if (i == ntA - 1) { finalize(); initGroup(gB); }
        cur ^= 1;
    }
    finalize();
}

// ---------------------------------------------------------------- launch
extern "C" void kernel_launch(void* const* d_in, const int* in_sizes, int n_in,
                              void* d_out, int out_size, void* d_ws, size_t ws_size,
                              hipStream_t stream) {
    const float* X  = (const float*)d_in[0];
    const float* Wq = (const float*)d_in[1];
    const float* Wk = (const float*)d_in[2];
    const float* Wv = (const float*)d_in[3];
    const float* Wo = (const float*)d_in[4];
    float* out = (float*)d_out;
    char* ws = (char*)d_ws;

    bf16* Xb    = (bf16*)(ws);                    // 16 MB (reused as Attn)
    bf16* WqkvT = (bf16*)(ws + (16u << 20));      //  6 MB [3072][1024]
    bf16* WoT   = (bf16*)(ws + (22u << 20));      //  2 MB
    bf16* Qb    = (bf16*)(ws + (24u << 20));      // 16 MB [bh][s][dk] (pre-scaled)
    bf16* Vt    = (bf16*)(ws + (56u << 20));      // 16 MB [bh][dk][s]
    bf16* Attn  = Xb;
    bf16* Kb    = Qb + (size_t)8388608;           // fused-QK second half

    prep_kernel<<<dim3(12288), dim3(256), 0, stream>>>(X, Wq, Wk, Wv, Wo,
                                                       Xb, WqkvT, WoT);

    gemm_qkv<<<dim3(1536), dim3(256), 0, stream>>>(Xb, WqkvT, Qb, Vt);

    attn_kernel<<<dim3(1024), dim3(256), 0, stream>>>(Qb, Kb, Vt, Attn);

    gemm_o<<<dim3(512), dim3(256), 0, stream>>>(Attn, WoT, out);
}

// Round 11
// 242.922 us; speedup vs baseline: 1.1136x; 1.0838x over previous
//
#include <hip/hip_runtime.h>

typedef __bf16 bf16;
typedef __attribute__((ext_vector_type(8))) __bf16 bf16x8;
typedef __attribute__((ext_vector_type(4))) float f32x4;
typedef __attribute__((ext_vector_type(4))) unsigned short u16x4;

#define D_MODEL 1024
#define SEQ     2048
#define NB      4
#define NH      16
#define DK      64
#define MROWS   (NB * SEQ)   // 8192

#define MFMA_BF16 __builtin_amdgcn_mfma_f32_16x16x32_bf16
#define EXP2F(x) __builtin_amdgcn_exp2f(x)
#define QSCALE 0.18033688011112042f   // 0.125 * log2(e)

__device__ __forceinline__ bf16 f2b(float f) {
    union { float f; unsigned u; } c; c.f = f;
    unsigned r = (c.u + 0x7fffu + ((c.u >> 16) & 1u)) >> 16;
    union { unsigned short s; bf16 b; } o; o.s = (unsigned short)r;
    return o.b;
}
__device__ __forceinline__ unsigned short f2u(float f) {
    union { float f; unsigned u; } c; c.f = f;
    return (unsigned short)((c.u + 0x7fffu + ((c.u >> 16) & 1u)) >> 16);
}
__device__ __forceinline__ unsigned fbits(float f) {
    union { float f; unsigned u; } c; c.f = f; return c.u;
}
// pack two fp32 -> two bf16 (truncation) in one v_perm_b32
__device__ __forceinline__ unsigned pack2(float lo, float hi) {
    return __builtin_amdgcn_perm(fbits(hi), fbits(lo), 0x07060302u);
}

template <int N> struct IC { static constexpr int v = N; };

// ---------------------------------------------------------------- prep (fused)
__global__ void prep_kernel(const float* __restrict__ X,
                            const float* __restrict__ Wq, const float* __restrict__ Wk,
                            const float* __restrict__ Wv, const float* __restrict__ Wo,
                            bf16* __restrict__ Xb, bf16* __restrict__ WqkvT,
                            bf16* __restrict__ WoT) {
    __shared__ float tile[32][33];
    const int bid = blockIdx.x;
    if (bid < 8192) {
        int i = bid * 256 + threadIdx.x;
        float4 v = ((const float4*)X)[i];
        u16x4 o; o[0] = f2u(v.x); o[1] = f2u(v.y); o[2] = f2u(v.z); o[3] = f2u(v.w);
        ((u16x4*)Xb)[i] = o;
    } else {
        int r = bid - 8192;
        int w = r >> 10, tl = r & 1023;
        const float* src = (w == 0) ? Wq : (w == 1) ? Wk : (w == 2) ? Wv : Wo;
        bf16* dst = (w == 3) ? WoT : WqkvT + (size_t)w * 1024 * 1024;
        const int n0 = (tl & 31) * 32, k0 = (tl >> 5) * 32;
        const int tx = threadIdx.x & 31, ty = threadIdx.x >> 5;
#pragma unroll
        for (int i = 0; i < 4; i++)
            tile[ty + i * 8][tx] = src[(size_t)(k0 + ty + i * 8) * 1024 + n0 + tx];
        __syncthreads();
#pragma unroll
        for (int i = 0; i < 4; i++)
            dst[(size_t)(n0 + ty + i * 8) * 1024 + k0 + tx] = f2b(tile[tx][ty + i * 8]);
    }
}

// ---------------------------------------------------------------- fused QKV GEMM
// (unchanged R8 config)
__global__ __launch_bounds__(256) void gemm_qkv(const bf16* __restrict__ A,
                                                const bf16* __restrict__ Bt,
                                                bf16* __restrict__ outQ,
                                                bf16* __restrict__ outV) {
    __shared__ __align__(16) bf16 lA[128 * 64];
    __shared__ __align__(16) bf16 lB[128 * 64];

    const int t = threadIdx.x;
    const int wid = t >> 6, lane = t & 63;
    const int ln = lane & 15, qd = lane >> 4;
    const int wm = wid >> 1, wn = wid & 1;

    const int bid = blockIdx.x;
    const int idx = bid >> 3;
    const int colb = (bid & 7) * 3 + (idx % 3);
    const int rowb = idx / 3;
    const int row0 = rowb * 128, col0 = colb * 128;
    const bool isQK = (col0 < 2048);

    const int srow = t >> 3;
    const int schunk = (t & 7) ^ (srow & 7);
    const bf16* ga = A  + (size_t)(row0 + srow) * 1024 + schunk * 8;
    const bf16* gb = Bt + (size_t)(col0 + srow) * 1024 + schunk * 8;
    const int swk = ln & 7;

    f32x4 acc[4][4];
#pragma unroll
    for (int i = 0; i < 4; i++)
#pragma unroll
        for (int j = 0; j < 4; j++) acc[i][j] = (f32x4){0.f, 0.f, 0.f, 0.f};

    for (int kb = 0; kb < 1024; kb += 64) {
#pragma unroll
        for (int c = 0; c < 4; c++) {
            __builtin_amdgcn_global_load_lds(
                (const __attribute__((address_space(1))) void*)(ga + kb + (size_t)c * 32 * 1024),
                (__attribute__((address_space(3))) void*)(&lA[t * 8 + c * 2048]), 16, 0, 0);
            __builtin_amdgcn_global_load_lds(
                (const __attribute__((address_space(1))) void*)(gb + kb + (size_t)c * 32 * 1024),
                (__attribute__((address_space(3))) void*)(&lB[t * 8 + c * 2048]), 16, 0, 0);
        }
        __syncthreads();

#pragma unroll
        for (int ks = 0; ks < 2; ks++) {
            bf16x8 af[4], bfr[4];
#pragma unroll
            for (int i = 0; i < 4; i++)
                af[i] = *(const bf16x8*)&lA[(wm * 64 + i * 16 + ln) * 64
                                            + ((ks * 4 + qd) ^ swk) * 8];
#pragma unroll
            for (int j = 0; j < 4; j++)
                bfr[j] = *(const bf16x8*)&lB[(wn * 64 + j * 16 + ln) * 64
                                             + ((ks * 4 + qd) ^ swk) * 8];
            if (isQK) {
#pragma unroll
                for (int i = 0; i < 4; i++)
#pragma unroll
                    for (int j = 0; j < 4; j++)
                        acc[i][j] = MFMA_BF16(bfr[j], af[i], acc[i][j], 0, 0, 0);
            } else {
#pragma unroll
                for (int i = 0; i < 4; i++)
#pragma unroll
                    for (int j = 0; j < 4; j++)
                        acc[i][j] = MFMA_BF16(af[i], bfr[j], acc[i][j], 0, 0, 0);
            }
        }
        __syncthreads();
    }

    if (isQK) {
#pragma unroll
        for (int i = 0; i < 4; i++)
#pragma unroll
            for (int j = 0; j < 4; j++) {
                int m  = row0 + wm * 64 + i * 16 + ln;
                int n0 = col0 + wn * 64 + j * 16 + qd * 4;
                float scale = (n0 < 1024) ? QSCALE : 1.0f;
                int b = m >> 11, s = m & 2047;
                int h = (n0 & 1023) >> 6, d0 = n0 & 63;
                size_t addr = (((size_t)(b * NH + h) * SEQ + s) * DK + d0)
                              + (size_t)(n0 >> 10) * 8388608;
                u16x4 w;
#pragma unroll
                for (int r = 0; r < 4; r++) w[r] = f2u(acc[i][j][r] * scale);
                *(u16x4*)&outQ[addr] = w;
            }
    } else {
#pragma unroll
        for (int i = 0; i < 4; i++)
#pragma unroll
            for (int j = 0; j < 4; j++) {
                int m0 = row0 + wm * 64 + i * 16 + qd * 4;
                int n  = col0 + wn * 64 + j * 16 + ln - 2048;
                int b = m0 >> 11, s0 = m0 & 2047;
                int h = n >> 6, d = n & 63;
                size_t addr = ((size_t)(b * NH + h) * DK + d) * SEQ + s0;
                u16x4 w;
#pragma unroll
                for (int r = 0; r < 4; r++) w[r] = f2u(acc[i][j][r]);
                *(u16x4*)&outV[addr] = w;
            }
    }
}

// ---------------------------------------------------------------- output GEMM
// (unchanged R8 config: 128x128, 512 blocks, XCD-pinned cols)
__global__ __launch_bounds__(256) void gemm_o(const bf16* __restrict__ A,
                                              const bf16* __restrict__ Bt,
                                              float* __restrict__ out) {
    __shared__ __align__(16) bf16 lA[128 * 64];
    __shared__ __align__(16) bf16 lB[128 * 64];

    const int t = threadIdx.x;
    const int wid = t >> 6, lane = t & 63;
    const int ln = lane & 15, qd = lane >> 4;
    const int wm = wid >> 1, wn = wid & 1;

    const int bid = blockIdx.x;
    const int colb = bid & 7, rowb = bid >> 3;
    const int row0 = rowb * 128, col0 = colb * 128;

    const int srow = t >> 3;
    const int schunk = (t & 7) ^ (srow & 7);
    const bf16* ga = A  + (size_t)(row0 + srow) * 1024 + schunk * 8;
    const bf16* gb = Bt + (size_t)(col0 + srow) * 1024 + schunk * 8;
    const int swk = ln & 7;

    f32x4 acc[4][4];
#pragma unroll
    for (int i = 0; i < 4; i++)
#pragma unroll
        for (int j = 0; j < 4; j++) acc[i][j] = (f32x4){0.f, 0.f, 0.f, 0.f};

    for (int kb = 0; kb < 1024; kb += 64) {
#pragma unroll
        for (int c = 0; c < 4; c++) {
            __builtin_amdgcn_global_load_lds(
                (const __attribute__((address_space(1))) void*)(ga + kb + (size_t)c * 32 * 1024),
                (__attribute__((address_space(3))) void*)(&lA[t * 8 + c * 2048]), 16, 0, 0);
            __builtin_amdgcn_global_load_lds(
                (const __attribute__((address_space(1))) void*)(gb + kb + (size_t)c * 32 * 1024),
                (__attribute__((address_space(3))) void*)(&lB[t * 8 + c * 2048]), 16, 0, 0);
        }
        __syncthreads();

#pragma unroll
        for (int ks = 0; ks < 2; ks++) {
            bf16x8 af[4], bfr[4];
#pragma unroll
            for (int i = 0; i < 4; i++)
                af[i] = *(const bf16x8*)&lA[(wm * 64 + i * 16 + ln) * 64
                                            + ((ks * 4 + qd) ^ swk) * 8];
#pragma unroll
            for (int j = 0; j < 4; j++)
                bfr[j] = *(const bf16x8*)&lB[(wn * 64 + j * 16 + ln) * 64
                                             + ((ks * 4 + qd) ^ swk) * 8];
#pragma unroll
            for (int i = 0; i < 4; i++)
#pragma unroll
                for (int j = 0; j < 4; j++)
                    acc[i][j] = MFMA_BF16(bfr[j], af[i], acc[i][j], 0, 0, 0);
        }
        __syncthreads();
    }

#pragma unroll
    for (int i = 0; i < 4; i++)
#pragma unroll
        for (int j = 0; j < 4; j++) {
            int m  = row0 + wm * 64 + i * 16 + ln;
            int n0 = col0 + wn * 64 + j * 16 + qd * 4;
            *(f32x4*)&out[(size_t)m * 1024 + n0] = acc[i][j];
        }
}

// ---------------------------------------------------------------- attention
// R6/R8 structure, with the step loop unrolled by 2 so the double-buffer
// index is a COMPILE-TIME constant: all LDS addresses become loop-invariant
// lane registers + ds immediate offsets (no per-step cur*8192 VALU math).
// Step 0 peeled (buf 0), then 16 pairs of (buf 1, buf 0) steps = 33 total.
__global__ __launch_bounds__(256) void attn_kernel(const bf16* __restrict__ Q,
                                                   const bf16* __restrict__ K,
                                                   const bf16* __restrict__ Vt,
                                                   bf16* __restrict__ attn_out) {
    __shared__ __align__(16) bf16 kbuf[2][64 * 64];
    __shared__ __align__(16) bf16 vbuf[2][64 * 64];
    __shared__ __align__(16) bf16 plds[4][16 * 64];

    const int t = threadIdx.x;
    const int wid = t >> 6, lane = t & 63;
    const int ln = lane & 15, qd = lane >> 4;

    const int bid = blockIdx.x;
    const int bh   = ((bid >> 7) << 3) | (bid & 7);   // XCD swizzle
    const int pair = (bid >> 3) & 15;
    const int gA = pair, gB = 31 - pair;
    const int ntA = gA + 1, ntT = 33;

    const bf16* Qh = Q  + (size_t)bh * SEQ * DK;
    const bf16* Kh = K  + (size_t)bh * SEQ * DK;
    const bf16* Vh = Vt + (size_t)bh * DK * SEQ;
    bf16* pw = &plds[wid][0];

    const int srow = t >> 3;
    const int schunk = (t & 7) ^ (srow & 7);
    const bf16* kgp = Kh + (size_t)srow * DK + schunk * 8;
    const bf16* vgp = Vh + (size_t)srow * SEQ + schunk * 8;
    const int swk = ln & 7;

    f32x4 o[4];
    float l;
    int qw0;
    bf16x8 qf0, qf1;

    auto stage = [&](int kb, int buf) {
#pragma unroll
        for (int c = 0; c < 2; c++) {
            __builtin_amdgcn_global_load_lds(
                (const __attribute__((address_space(1))) void*)(kgp + (size_t)(kb + c * 32) * DK),
                (__attribute__((address_space(3))) void*)(&kbuf[buf][t * 8 + c * 2048]), 16, 0, 0);
            __builtin_amdgcn_global_load_lds(
                (const __attribute__((address_space(1))) void*)(vgp + (size_t)c * 32 * SEQ + kb),
                (__attribute__((address_space(3))) void*)(&vbuf[buf][t * 8 + c * 2048]), 16, 0, 0);
        }
    };
    auto initGroup = [&](int g) {
        qw0 = g * 64 + wid * 16;
        qf0 = *(const bf16x8*)(Qh + (size_t)(qw0 + ln) * DK + qd * 8);
        qf1 = *(const bf16x8*)(Qh + (size_t)(qw0 + ln) * DK + 32 + qd * 8);
#pragma unroll
        for (int c = 0; c < 4; c++) o[c] = (f32x4){0.f, 0.f, 0.f, 0.f};
        l = 0.f;
    };
    const int b = bh >> 4, h = bh & 15;
    auto finalize = [&]() {
        float ll = l;
        ll += __shfl_xor(ll, 16);
        ll += __shfl_xor(ll, 32);
        float inv = 1.0f / ll;
        size_t orow = ((size_t)(b * SEQ + qw0 + ln)) * D_MODEL + h * DK;
#pragma unroll
        for (int c = 0; c < 4; c++) {
            u16x4 w;
#pragma unroll
            for (int r = 0; r < 4; r++) w[r] = f2u(o[c][r] * inv);
            *(u16x4*)&attn_out[orow + c * 16 + qd * 4] = w;
        }
    };

    auto step = [&](auto curc, int i) {
        constexpr int CUR = decltype(curc)::v;
        __syncthreads();
        int nx = i + 1;
        if (nx < ntT) {
            int kbn = ((nx < ntA) ? nx : nx - ntA) * 64;
            stage(kbn, CUR ^ 1);
        }
        const int kb = ((i < ntA) ? i : i - ntA) * 64;
        const int nkk = min(4, max(0, ((qw0 + 15 - kb) >> 4) + 1));

        if (nkk > 0) {
            f32x4 st[4];
#pragma unroll
            for (int kk = 0; kk < 4; kk++)
                if (kk < nkk) {
                    const bf16* base = &kbuf[CUR][(kk * 16 + ln) * 64];
                    bf16x8 kf0 = *(const bf16x8*)(base + ((qd    ) ^ swk) * 8);
                    bf16x8 kf1 = *(const bf16x8*)(base + ((qd + 4) ^ swk) * 8);
                    f32x4 z = (f32x4){0.f, 0.f, 0.f, 0.f};
                    st[kk] = MFMA_BF16(kf0, qf0, z, 0, 0, 0);
                    st[kk] = MFMA_BF16(kf1, qf1, st[kk], 0, 0, 0);
                }

            float ps = 0.f;
#pragma unroll
            for (int kk = 0; kk < 4; kk++) {
                unsigned pk0 = 0, pk1 = 0;
                if (kk < nkk) {
                    f32x4 s = st[kk];
                    if (kb + kk * 16 == qw0) {
#pragma unroll
                        for (int r = 0; r < 4; r++)
                            if (qd * 4 + r > ln) s[r] = -INFINITY;
                    }
                    float p0 = EXP2F(s[0]);
                    float p1 = EXP2F(s[1]);
                    float p2 = EXP2F(s[2]);
                    float p3 = EXP2F(s[3]);
                    ps += (p0 + p1) + (p2 + p3);
                    pk0 = pack2(p0, p1);
                    pk1 = pack2(p2, p3);
                }
                int cw = 2 * kk + (qd >> 1);
                *(uint2*)&pw[ln * 64 + (cw ^ swk) * 8 + (qd & 1) * 4] =
                    make_uint2(pk0, pk1);
            }
            l += ps;

            asm volatile("s_waitcnt lgkmcnt(0)" ::: "memory");

#pragma unroll
            for (int half = 0; half < 2; half++)
                if (half == 0 || nkk > 2) {
                    bf16x8 pa = *(const bf16x8*)&pw[ln * 64 + ((half * 4 + qd) ^ swk) * 8];
#pragma unroll
                    for (int c = 0; c < 4; c++) {
                        bf16x8 vf = *(const bf16x8*)&vbuf[CUR][(c * 16 + ln) * 64
                                        + ((half * 4 + qd) ^ swk) * 8];
                        o[c] = MFMA_BF16(vf, pa, o[c], 0, 0, 0);
                    }
                }
        }

        if (i == ntA - 1) { finalize(); initGroup(gB); }
    };

    stage(0, 0);
    initGroup(gA);

    step(IC<0>{}, 0);
    for (int ii = 0; ii < 16; ii++) {
        step(IC<1>{}, 2 * ii + 1);
        step(IC<0>{}, 2 * ii + 2);
    }
    finalize();
}

// ---------------------------------------------------------------- launch
extern "C" void kernel_launch(void* const* d_in, const int* in_sizes, int n_in,
                              void* d_out, int out_size, void* d_ws, size_t ws_size,
                              hipStream_t stream) {
    const float* X  = (const float*)d_in[0];
    const float* Wq = (const float*)d_in[1];
    const float* Wk = (const float*)d_in[2];
    const float* Wv = (const float*)d_in[3];
    const float* Wo = (const float*)d_in[4];
    float* out = (float*)d_out;
    char* ws = (char*)d_ws;

    bf16* Xb    = (bf16*)(ws);                    // 16 MB (reused as Attn)
    bf16* WqkvT = (bf16*)(ws + (16u << 20));      //  6 MB [3072][1024]
    bf16* WoT   = (bf16*)(ws + (22u << 20));      //  2 MB
    bf16* Qb    = (bf16*)(ws + (24u << 20));      // 16 MB [bh][s][dk] (pre-scaled)
    bf16* Vt    = (bf16*)(ws + (56u << 20));      // 16 MB [bh][dk][s]
    bf16* Attn  = Xb;
    bf16* Kb    = Qb + (size_t)8388608;           // fused-QK second half

    prep_kernel<<<dim3(12288), dim3(256), 0, stream>>>(X, Wq, Wk, Wv, Wo,
                                                       Xb, WqkvT, WoT);

    gemm_qkv<<<dim3(1536), dim3(256), 0, stream>>>(Xb, WqkvT, Qb, Vt);

    attn_kernel<<<dim3(1024), dim3(256), 0, stream>>>(Qb, Kb, Vt, Attn);

    gemm_o<<<dim3(512), dim3(256), 0, stream>>>(Attn, WoT, out);
}